// Round 5
// baseline (911.294 us; speedup 1.0000x reference)
//
#include <hip/hip_runtime.h>
#include <stdint.h>

typedef short bf8 __attribute__((ext_vector_type(8)));   // 8 bf16 (4 VGPRs)
typedef float f4  __attribute__((ext_vector_type(4)));   // MFMA acc
typedef unsigned short u16;
typedef unsigned long long u64;

#define LOG2E 1.4426950408889634f

__device__ __forceinline__ u16 f2bf(float f){
  uint32_t u = __builtin_bit_cast(uint32_t, f);
  u += 0x7fffu + ((u >> 16) & 1u);
  return (u16)(u >> 16);
}
// sigmoid of value pre-scaled by log2e: 1/(1+2^-a)
__device__ __forceinline__ float sigm_ps(float a){
  return __builtin_amdgcn_rcpf(1.0f + __builtin_amdgcn_exp2f(-a));
}
// LDS-only barrier: do NOT drain vmcnt (keeps global stores/loads in flight)
__device__ __forceinline__ void bar_lds(){
  asm volatile("s_waitcnt lgkmcnt(0)\n\ts_barrier" ::: "memory");
}

// ---------------------------------------------------------------------------
// Prep: prescaled bf16 weights W0c[512][160]=[Whh0|Wih0|0], W1c[512][256]=
// [Whh1|Wih1]; rows scaled log2e (i,f,o) / 2*log2e (g); prescaled biases;
// zero the 256 publish flags (ws is poisoned 0xAA before every launch!).
// ---------------------------------------------------------------------------
__global__ void prep_kernel(const float* __restrict__ Wih0, const float* __restrict__ Whh0,
                            const float* __restrict__ bih0, const float* __restrict__ bhh0,
                            const float* __restrict__ Wih1, const float* __restrict__ Whh1,
                            const float* __restrict__ bih1, const float* __restrict__ bhh1,
                            u16* __restrict__ W0c, u16* __restrict__ W1c,
                            float* __restrict__ bias0, float* __restrict__ bias1,
                            int* __restrict__ flags){
  int g = blockIdx.x;      // gate row 0..511
  int t = threadIdx.x;     // 0..63
  float s = (g >= 256 && g < 384) ? 2.0f * LOG2E : LOG2E;
  for(int k = t; k < 160; k += 64){
    float v = 0.0f;
    if(k < 128)      v = Whh0[g*128 + k];
    else if(k < 146) v = Wih0[g*18 + (k-128)];
    W0c[g*160 + k] = f2bf(v * s);
  }
  for(int k = t; k < 256; k += 64){
    float v = (k < 128) ? Whh1[g*128 + k] : Wih1[g*128 + (k-128)];
    W1c[g*256 + k] = f2bf(v * s);
  }
  if(t == 0){
    bias0[g] = (bih0[g] + bhh0[g]) * s;
    bias1[g] = (bih1[g] + bhh1[g]) * s;
  }
  if(g < 4) flags[g*64 + t] = 0;   // 256 flags = 32 rowblocks x 8 waves
}

// ---------------------------------------------------------------------------
// Fused 2-layer LSTM, gate-major MFMA, producer/consumer overlap WITHOUT
// vmcnt drains on the critical path.
// 64 blocks x 512 threads. bid<32: L0-role (rows rb*16..+16), else L1-role.
// L0 publishes per-wave flags[rb*8+w] = t-1 after s_waitcnt vmcnt(4)
// (guarantees h1(<=t-2) complete at the device-coherent point, stall-free).
// L1 confirms flags (prefetched 1 iter ahead, register compare) BEFORE
// issuing h1 data loads; spin fallback only in the bootstrap transient.
// Step barriers are LDS-only (s_waitcnt lgkmcnt(0); s_barrier).
// ---------------------------------------------------------------------------
__global__ __launch_bounds__(512, 2)
void lstm_fused(const u16* __restrict__ Wc0, const u16* __restrict__ Wc1,
                const float* __restrict__ bias0, const float* __restrict__ bias1,
                const float* __restrict__ xin,   // (512,512,18) f32
                u64* __restrict__ h1g,           // [T][512 rows][32 u64] bf16x4
                int* __restrict__ flags,         // [32 rb][8 waves]
                const float* __restrict__ Wfc1, const float* __restrict__ bfc1,
                const float* __restrict__ Wfc2, const float* __restrict__ bfc2,
                float* __restrict__ out)         // (512,) f32
{
  __shared__ __align__(16) u16  hb[2][16][264];  // [buf][row][K-slots(+pad)]
  __shared__ __align__(16) float ffin[16][132];  // final h2 f32 for FC head

  const int tid  = threadIdx.x;
  const int wave = tid >> 6;
  const int lane = tid & 63;
  const int quad = lane >> 4;
  const int l15  = lane & 15;
  const bool isL0 = (blockIdx.x < 32);
  const int rb   = isL0 ? blockIdx.x : (blockIdx.x - 32);
  const int rowbase = rb * 16;

  // zero both LDS buffers (zeros double as h=0 init and K-padding)
  for(int i = tid; i < 2*16*264; i += 512) ((u16*)hb)[i] = 0;

  if(isL0){
    // ---------------- L0 role: K=160 = [h0(128) | x(18) | 0(14)], KT=5 ----
    bf8 A[4][5];
#pragma unroll
    for(int q = 0; q < 4; q++){
      const u16* wp = Wc0 + (u64)(128*q + 16*wave + l15)*160 + quad*8;
#pragma unroll
      for(int kt = 0; kt < 5; kt++) A[q][kt] = *(const bf8*)(wp + kt*32);
    }
    f4 bini[4];
#pragma unroll
    for(int q = 0; q < 4; q++) bini[q] = *(const f4*)(bias0 + 128*q + 16*wave + quad*4);
    float c[4] = {0.f,0.f,0.f,0.f};

    __syncthreads();
    // stage x(0)
    if(tid < 288){
      int r = tid/18, k = tid - 18*r;
      hb[0][r][128+k] = f2bf(xin[((u64)(rowbase+r)*512 + 0)*18 + k]);
    }
    __syncthreads();

    int sr = 0, sk = 0;
    if(tid < 288){ sr = tid/18; sk = tid - 18*sr; }

    for(int t = 0; t < 512; t++){
      const int cur = t & 1, nxt = cur ^ 1;
      // prefetch x(t+1)
      float xv = 0.f;
      if(tid < 288 && t < 511)
        xv = xin[((u64)(rowbase+sr)*512 + (t+1))*18 + sk];

      bf8 B[5];
      const u16* br = &hb[cur][l15][quad*8];
#pragma unroll
      for(int kt = 0; kt < 5; kt++) B[kt] = *(const bf8*)(br + kt*32);

      f4 acc[4];
#pragma unroll
      for(int q = 0; q < 4; q++) acc[q] = bini[q];
#pragma unroll
      for(int kt = 0; kt < 5; kt++){
#pragma unroll
        for(int q = 0; q < 4; q++)
          acc[q] = __builtin_amdgcn_mfma_f32_16x16x32_bf16(A[q][kt], B[kt], acc[q], 0,0,0);
      }

      // in-register update: comps j=16w+quad*4+r, row l15
      u64 hpack; u16* hp = (u16*)&hpack;
#pragma unroll
      for(int r = 0; r < 4; r++){
        float ig = sigm_ps(acc[0][r]);
        float fg = sigm_ps(acc[1][r]);
        float gg = 2.f*sigm_ps(acc[2][r]) - 1.f;
        float og = sigm_ps(acc[3][r]);
        c[r] = fg*c[r] + ig*gg;
        float th = 2.f*sigm_ps(c[r]*(2.f*LOG2E)) - 1.f;
        hp[r] = f2bf(og*th);
      }
      *(u64*)(&hb[nxt][l15][16*wave + quad*4]) = hpack;
      if(tid < 288 && t < 511) hb[nxt][sr][128+sk] = f2bf(xv);
      // publish h1(t) device-visible (agent-coherent store; NOT drained here)
      __hip_atomic_store(h1g + ((u64)t*512 + rowbase + l15)*32 + 4*wave + quad,
                         hpack, __ATOMIC_RELAXED, __HIP_MEMORY_SCOPE_AGENT);
      // delayed per-wave flag: after vmcnt(4), store(t-2) is complete -> F=t-1
      if(t >= 1){
        asm volatile("s_waitcnt vmcnt(4)" ::: "memory");
        if(lane == 0)
          __hip_atomic_store(flags + rb*8 + wave, t - 1,
                             __ATOMIC_RELAXED, __HIP_MEMORY_SCOPE_AGENT);
      }
      bar_lds();
    }
    // final publish: everything drained -> F=512
    asm volatile("s_waitcnt vmcnt(0)" ::: "memory");
    if(lane == 0)
      __hip_atomic_store(flags + rb*8 + wave, 512,
                         __ATOMIC_RELAXED, __HIP_MEMORY_SCOPE_AGENT);
  } else {
    // ---------------- L1 role: K=256 = [h2(128) | h1(128)], KT=8 ----------
    bf8 A[4][8];
#pragma unroll
    for(int q = 0; q < 4; q++){
      const u16* wp = Wc1 + (u64)(128*q + 16*wave + l15)*256 + quad*8;
#pragma unroll
      for(int kt = 0; kt < 8; kt++) A[q][kt] = *(const bf8*)(wp + kt*32);
    }
    f4 bini[4];
#pragma unroll
    for(int q = 0; q < 4; q++) bini[q] = *(const f4*)(bias1 + 128*q + 16*wave + quad*4);
    float c[4] = {0.f,0.f,0.f,0.f};

    const int pr = tid >> 5;          // staging row
    const int pu = tid & 31;          // staging u64-chunk (4 comps)

    __syncthreads();
    // ---- bootstrap: wait for h1(0), stage into buf0
    {
      int Fv = 0;
      bool ok = (lane >= 8);
      if(lane < 8) Fv = __hip_atomic_load(flags + rb*8 + lane,
                                          __ATOMIC_RELAXED, __HIP_MEMORY_SCOPE_AGENT);
      ok = (lane < 8) ? (Fv >= 1) : true;
      while(!__all(ok)){
        __builtin_amdgcn_s_sleep(4);
        if(lane < 8) Fv = __hip_atomic_load(flags + rb*8 + lane,
                                            __ATOMIC_RELAXED, __HIP_MEMORY_SCOPE_AGENT);
        ok = (lane < 8) ? (Fv >= 1) : true;
      }
      u64 v = __hip_atomic_load(h1g + ((u64)0*512 + rowbase + pr)*32 + pu,
                                __ATOMIC_RELAXED, __HIP_MEMORY_SCOPE_AGENT);
      *(u64*)(&hb[0][pr][128 + pu*4]) = v;
    }
    __syncthreads();

    // prefetch flags for iter 0's confirm
    int Fv = 0;
    if(lane < 8) Fv = __hip_atomic_load(flags + rb*8 + lane,
                                        __ATOMIC_RELAXED, __HIP_MEMORY_SCOPE_AGENT);

    float hv[4];
    for(int t = 0; t < 512; t++){
      const int cur = t & 1, nxt = cur ^ 1;
      u64 pv = 0;
      if(t < 511){
        // ---- confirm h1(t+1) published: fast path = register compare
        const int need = t + 2;
        bool ok = (lane < 8) ? (Fv >= need) : true;
        while(!__all(ok)){
          __builtin_amdgcn_s_sleep(2);
          if(lane < 8) Fv = __hip_atomic_load(flags + rb*8 + lane,
                                              __ATOMIC_RELAXED, __HIP_MEMORY_SCOPE_AGENT);
          ok = (lane < 8) ? (Fv >= need) : true;
        }
        // data loads issue only AFTER confirm (flag value already consumed)
        pv = __hip_atomic_load(h1g + ((u64)(t+1)*512 + rowbase + pr)*32 + pu,
                               __ATOMIC_RELAXED, __HIP_MEMORY_SCOPE_AGENT);
        // prefetch flags for next iteration's confirm
        if(lane < 8) Fv = __hip_atomic_load(flags + rb*8 + lane,
                                            __ATOMIC_RELAXED, __HIP_MEMORY_SCOPE_AGENT);
      }

      bf8 B[8];
      const u16* br = &hb[cur][l15][quad*8];
#pragma unroll
      for(int kt = 0; kt < 8; kt++) B[kt] = *(const bf8*)(br + kt*32);

      f4 acc[4];
#pragma unroll
      for(int q = 0; q < 4; q++) acc[q] = bini[q];
#pragma unroll
      for(int kt = 0; kt < 8; kt++){
#pragma unroll
        for(int q = 0; q < 4; q++)
          acc[q] = __builtin_amdgcn_mfma_f32_16x16x32_bf16(A[q][kt], B[kt], acc[q], 0,0,0);
      }

      u64 hpack; u16* hp = (u16*)&hpack;
#pragma unroll
      for(int r = 0; r < 4; r++){
        float ig = sigm_ps(acc[0][r]);
        float fg = sigm_ps(acc[1][r]);
        float gg = 2.f*sigm_ps(acc[2][r]) - 1.f;
        float og = sigm_ps(acc[3][r]);
        c[r] = fg*c[r] + ig*gg;
        float th = 2.f*sigm_ps(c[r]*(2.f*LOG2E)) - 1.f;
        hv[r] = og*th;
        hp[r] = f2bf(hv[r]);
      }
      *(u64*)(&hb[nxt][l15][16*wave + quad*4]) = hpack;
      if(t < 511) *(u64*)(&hb[nxt][pr][128 + pu*4]) = pv;
      bar_lds();
    }
    // stash final h2 (f32) for FC head
#pragma unroll
    for(int r = 0; r < 4; r++) ffin[l15][16*wave + quad*4 + r] = hv[r];
    __syncthreads();

    // ---- FC head: per row r, 64 hidden, 32 threads x 2v each
    {
      int r = tid >> 5, u = tid & 31;
      float s0 = bfc1[2*u], s1 = bfc1[2*u+1];
      const float* w0 = Wfc1 + (2*u)*128;
      const float* w1 = Wfc1 + (2*u+1)*128;
      for(int j = 0; j < 128; j++){
        float h = ffin[r][j];
        s0 = fmaf(w0[j], h, s0);
        s1 = fmaf(w1[j], h, s1);
      }
      float term = fmaxf(s0, 0.f)*Wfc2[2*u] + fmaxf(s1, 0.f)*Wfc2[2*u+1];
#pragma unroll
      for(int off = 16; off > 0; off >>= 1) term += __shfl_down(term, off, 32);
      if(u == 0) out[rowbase + r] = sigm_ps((term + bfc2[0]) * LOG2E);
    }
  }
}

// ---------------------------------------------------------------------------
extern "C" void kernel_launch(void* const* d_in, const int* in_sizes, int n_in,
                              void* d_out, int out_size, void* d_ws, size_t ws_size,
                              hipStream_t stream){
  const float* x    = (const float*)d_in[0];
  const float* Wih0 = (const float*)d_in[1];
  const float* Whh0 = (const float*)d_in[2];
  const float* bih0 = (const float*)d_in[3];
  const float* bhh0 = (const float*)d_in[4];
  const float* Wih1 = (const float*)d_in[5];
  const float* Whh1 = (const float*)d_in[6];
  const float* bih1 = (const float*)d_in[7];
  const float* bhh1 = (const float*)d_in[8];
  const float* Wfc1 = (const float*)d_in[9];
  const float* bfc1 = (const float*)d_in[10];
  const float* Wfc2 = (const float*)d_in[11];
  const float* bfc2 = (const float*)d_in[12];

  char* ws = (char*)d_ws;
  u16*   W0c   = (u16*)(ws);                       // 512*160*2 = 163840 B
  u16*   W1c   = (u16*)(ws + 163840);              // 512*256*2 = 262144 B
  float* bias0 = (float*)(ws + 163840 + 262144);   // 2048 B
  float* bias1 = bias0 + 512;                      // 2048 B
  int*   flags = (int*)(ws + 163840 + 262144 + 4096);  // 1024 B (256 int)
  u64*   h1g   = (u64*)(ws + 163840 + 262144 + 4096 + 1024); // 64 MiB

  prep_kernel<<<dim3(512), dim3(64), 0, stream>>>(Wih0, Whh0, bih0, bhh0,
                                                  Wih1, Whh1, bih1, bhh1,
                                                  W0c, W1c, bias0, bias1, flags);

  lstm_fused<<<dim3(64), dim3(512), 0, stream>>>(
      W0c, W1c, bias0, bias1, x, h1g, flags,
      Wfc1, bfc1, Wfc2, bfc2, (float*)d_out);
}